// Round 9
// baseline (358.069 us; speedup 1.0000x reference)
//
#include <hip/hip_runtime.h>
#include <hip/hip_bf16.h>

typedef __bf16 bf16;
typedef __attribute__((ext_vector_type(8))) __bf16 bf16x8;
typedef __attribute__((ext_vector_type(4))) __bf16 bf16x4;
typedef __attribute__((ext_vector_type(4))) float f32x4;
typedef __attribute__((ext_vector_type(16))) float f32x16;

// async global->LDS: stages 16B per lane; LDS dest = uniform base + lane*16
__device__ __forceinline__ void glds16(const bf16* g, bf16* l)
{
  __builtin_amdgcn_global_load_lds(
      (const __attribute__((address_space(1))) unsigned int*)g,
      (__attribute__((address_space(3))) unsigned int*)l, 16, 0, 0);
}

__device__ __forceinline__ unsigned pk_bf16(float lo, float hi)
{
  unsigned r;
  asm("v_cvt_pk_bf16_f32 %0, %1, %2" : "=v"(r) : "v"(lo), "v"(hi));
  return r;
}
__device__ __forceinline__ void plswap(unsigned& a, unsigned& b)
{
  asm volatile("v_permlane32_swap_b32 %0, %1" : "+v"(a), "+v"(b));
}
__device__ __forceinline__ float2 swap_halves(float x)
{
  unsigned a = __float_as_uint(x), b = a;
  plswap(a, b);
  return make_float2(__uint_as_float(a), __uint_as_float(b));
}
// raw v_exp_f32: 2^x, single instruction (exp2f() libcall was +15us, round 7)
__device__ __forceinline__ float fexp2(float x)
{
  float r;
  asm("v_exp_f32 %0, %1" : "=v"(r) : "v"(x));
  return r;
}

// bijective XCD-chunked remap of the flat workgroup id (m204 formula)
__device__ __forceinline__ int xcd_swz_id(int gx, int gy)
{
  int nwg = gx * gy;
  int bid = blockIdx.y * gx + blockIdx.x;
  int q = nwg >> 3, r = nwg & 7;
  int xcd = bid & 7, idx = bid >> 3;
  return (xcd < r) ? (xcd * (q + 1) + idx) : (r * (q + 1) + (xcd - r) * q + idx);
}

// ---------------------------------------------------------------------------
// merged weight convert f32 -> bf16 (10 segments, one launch)
// ---------------------------------------------------------------------------
struct CvtPack {
  const float* src[10];
  bf16* dst[10];
  int end4[10];
};

__global__ __launch_bounds__(256) void cvt_many(CvtPack p, int total4)
{
  int i = blockIdx.x * 256 + threadIdx.x;
  if (i >= total4) return;
  int s = 0;
#pragma unroll
  for (int k = 0; k < 9; k++) s += (i >= p.end4[k]) ? 1 : 0;
  int base = s ? p.end4[s - 1] : 0;
  long j = (long)(i - base) * 4;
  f32x4 v = *(const f32x4*)(p.src[s] + j);
  bf16x4 r;
  r.x = (bf16)v.x; r.y = (bf16)v.y; r.z = (bf16)v.z; r.w = (bf16)v.w;
  *(bf16x4*)(p.dst[s] + j) = r;
}

// ---------------------------------------------------------------------------
// transpose per z: in [R][C] f32 -> out [C][R] (f32 or bf16)
// ---------------------------------------------------------------------------
template <typename OutT>
__global__ __launch_bounds__(256) void transpose_k(const float* __restrict__ in,
                                                   OutT* __restrict__ out, int R, int C)
{
  __shared__ float tile[32][33];
  long zoff = (long)blockIdx.z * R * C;
  in += zoff; out += zoff;
  int c0 = blockIdx.x * 32, r0 = blockIdx.y * 32;
  int tx = threadIdx.x & 31, ty = threadIdx.x >> 5;
  for (int i = ty; i < 32; i += 8)
    tile[i][tx] = in[(long)(r0 + i) * C + c0 + tx];
  __syncthreads();
  for (int i = ty; i < 32; i += 8)
    out[(long)(c0 + i) * R + r0 + tx] = (OutT)tile[tx][i];
}

// ---------------------------------------------------------------------------
// LayerNorm rows of 512, fp32 in, bf16 out; one wave per row
// ---------------------------------------------------------------------------
__global__ __launch_bounds__(256) void ln_rows(const float* __restrict__ x,
                                               const float* __restrict__ g,
                                               bf16* __restrict__ out)
{
  int row = blockIdx.x * 4 + (threadIdx.x >> 6);
  int lane = threadIdx.x & 63;
  const float* xr = x + (long)row * 512;
  f32x4 a = *(const f32x4*)(xr + lane * 4);
  f32x4 b = *(const f32x4*)(xr + 256 + lane * 4);
  float s = a.x + a.y + a.z + a.w + b.x + b.y + b.z + b.w;
  float q = a.x*a.x + a.y*a.y + a.z*a.z + a.w*a.w
          + b.x*b.x + b.y*b.y + b.z*b.z + b.w*b.w;
#pragma unroll
  for (int off = 32; off; off >>= 1) {
    s += __shfl_xor(s, off);
    q += __shfl_xor(q, off);
  }
  float mean = s * (1.f / 512.f);
  float var  = q * (1.f / 512.f) - mean * mean;
  float rs = rsqrtf(var + 1e-5f);
  f32x4 ga = *(const f32x4*)(g + lane * 4);
  f32x4 gb = *(const f32x4*)(g + 256 + lane * 4);
  bf16* orow = out + (long)row * 512;
  bf16x4 r0, r1;
  r0.x = (bf16)((a.x - mean) * rs * ga.x);
  r0.y = (bf16)((a.y - mean) * rs * ga.y);
  r0.z = (bf16)((a.z - mean) * rs * ga.z);
  r0.w = (bf16)((a.w - mean) * rs * ga.w);
  r1.x = (bf16)((b.x - mean) * rs * gb.x);
  r1.y = (bf16)((b.y - mean) * rs * gb.y);
  r1.z = (bf16)((b.z - mean) * rs * gb.z);
  r1.w = (bf16)((b.w - mean) * rs * gb.w);
  *(bf16x4*)(orow + lane * 4) = r0;
  *(bf16x4*)(orow + 256 + lane * 4) = r1;
}

// ---------------------------------------------------------------------------
// NT GEMM: D[M][N] = A[M][K] * B[N][K]^T
// 3-buffer LDS, depth-2 counted vmcnt; XCD chunks now span COL-tiles for a
// few ROW-stripes (bx = w/gy) so each XCD keeps its A-stripes L2-resident
// and A is fetched from HBM once total (was: every XCD refetched all of A).
// ---------------------------------------------------------------------------
template <int BN>
__global__ __launch_bounds__(256) void gemm_nt(
    const bf16* __restrict__ A, long sAz,
    const bf16* __restrict__ B, long sBz,
    int M, int N, int K,
    void* __restrict__ Dp, long sDz, int ldd,
    const float* __restrict__ bias,
    const float* __restrict__ resid,
    int mode)
{
  constexpr int NI = BN / 32;
  __shared__ bf16 As[3][128 * 32];
  __shared__ bf16 Bs[3][BN * 32];
  const int tid = threadIdx.x;
  const int lane = tid & 63;
  const int wave = tid >> 6;
  const int l15 = lane & 15, lg = lane >> 4;
  const int wm = (wave & 1) << 6;
  const int wn = (BN == 128) ? ((wave >> 1) << 6) : ((wave >> 1) << 5);
  const long z = blockIdx.z;

  int bx, by;
  if (gridDim.z == 1) {
    int w = xcd_swz_id(gridDim.x, gridDim.y);
    bx = w / gridDim.y; by = w % gridDim.y;   // A-row-stripe stays on one XCD
  } else { bx = blockIdx.x; by = blockIdx.y; }

  const bf16* Ab = A + z * sAz + (long)(bx * 128) * K;
  const bf16* Bb = B + z * sBz + (long)(by * BN) * K;

  const int srow = lane >> 2;
  const int schunk = (lane & 3) * 8;
  const bf16* gA = Ab + (long)(wave * 32 + srow) * K + schunk;
  const int lAoff = wave * 1024;
  const bf16* gB;
  int lBoff;
  if (BN == 128) { gB = Bb + (long)(wave * 32 + srow) * K + schunk; lBoff = wave * 1024; }
  else           { gB = Bb + (long)(wave * 16 + srow) * K + schunk; lBoff = wave * 512; }

  f32x4 acc[4][NI] = {};

  auto STAGE = [&](int buf, int t) {
    int k0 = t << 5;
    glds16(gA + k0, &As[buf][lAoff]);
    glds16(gA + 16 * K + k0, &As[buf][lAoff + 512]);
    glds16(gB + k0, &Bs[buf][lBoff]);
    if (BN == 128) glds16(gB + 16 * K + k0, &Bs[buf][lBoff + 512]);
  };

  const int nt = K >> 5;
  STAGE(0, 0);
  STAGE(1, 1);

  int cur = 0;
  for (int t = 0; t < nt; ++t) {
    if (t + 2 < nt) {
      int sb = cur + 2; if (sb >= 3) sb -= 3;
      STAGE(sb, t + 2);
      if constexpr (BN == 128) asm volatile("s_waitcnt vmcnt(8)" ::: "memory");
      else                     asm volatile("s_waitcnt vmcnt(6)" ::: "memory");
    } else if (t + 2 == nt) {
      if constexpr (BN == 128) asm volatile("s_waitcnt vmcnt(4)" ::: "memory");
      else                     asm volatile("s_waitcnt vmcnt(3)" ::: "memory");
    } else {
      asm volatile("s_waitcnt vmcnt(0)" ::: "memory");
    }
    __builtin_amdgcn_s_barrier();
    __builtin_amdgcn_sched_barrier(0);

    bf16x8 af[4], bfr[NI];
#pragma unroll
    for (int i = 0; i < 4; i++)
      af[i] = *(const bf16x8*)(&As[cur][(wm + i * 16 + l15) * 32 + 8 * lg]);
#pragma unroll
    for (int i = 0; i < NI; i++)
      bfr[i] = *(const bf16x8*)(&Bs[cur][(wn + i * 16 + l15) * 32 + 8 * lg]);
    __builtin_amdgcn_s_setprio(1);
#pragma unroll
    for (int mi = 0; mi < 4; mi++)
#pragma unroll
      for (int ni = 0; ni < NI; ni++)
        acc[mi][ni] = __builtin_amdgcn_mfma_f32_16x16x32_bf16(af[mi], bfr[ni],
                                                              acc[mi][ni], 0, 0, 0);
    __builtin_amdgcn_s_setprio(0);
    asm volatile("s_waitcnt lgkmcnt(0)" ::: "memory");
    __builtin_amdgcn_sched_barrier(0);
    __builtin_amdgcn_s_barrier();
    cur = (cur == 2) ? 0 : cur + 1;
  }

  const int gr0 = bx * 128 + wm;
  const int gc0 = by * BN + wn;
#pragma unroll
  for (int ni = 0; ni < NI; ni++) {
    int gc = gc0 + ni * 16 + l15;
    float bv = bias ? bias[gc] : 0.f;
#pragma unroll
    for (int mi = 0; mi < 4; mi++) {
#pragma unroll
      for (int rr = 0; rr < 4; rr++) {
        int gr = gr0 + mi * 16 + 4 * lg + rr;
        long o = z * sDz + (long)gr * ldd + gc;
        float val = acc[mi][ni][rr] + bv;
        if (mode == 0) ((bf16*)Dp)[o] = (bf16)val;
        else           ((float*)Dp)[o] = val + resid[o];
      }
    }
  }
}

// ---------------------------------------------------------------------------
// Fused GEGLU dual-GEMM (same chunk-orientation fix)
// ---------------------------------------------------------------------------
__global__ __launch_bounds__(256) void gemm_geglu(
    const bf16* __restrict__ A,
    const bf16* __restrict__ WH, const bf16* __restrict__ WG,
    const float* __restrict__ bH, const float* __restrict__ bG,
    bf16* __restrict__ D, int K)
{
  __shared__ bf16 As[3][128 * 32];
  __shared__ bf16 Hs[3][64 * 32];
  __shared__ bf16 Gs[3][64 * 32];
  const int tid = threadIdx.x;
  const int lane = tid & 63;
  const int wave = tid >> 6;
  const int l15 = lane & 15, lg = lane >> 4;
  const int wm = (wave & 1) << 6;
  const int wn = (wave >> 1) << 5;

  int w = xcd_swz_id(gridDim.x, gridDim.y);
  int bx = w / gridDim.y, by = w % gridDim.y;   // A-row-stripe per XCD

  const bf16* Ab = A + (long)(bx * 128) * K;
  const bf16* Hb = WH + (long)(by * 64) * K;
  const bf16* Gb = WG + (long)(by * 64) * K;

  const int srow = lane >> 2;
  const int schunk = (lane & 3) * 8;
  const bf16* gA = Ab + (long)(wave * 32 + srow) * K + schunk;
  const bf16* gH = Hb + (long)(wave * 16 + srow) * K + schunk;
  const bf16* gG = Gb + (long)(wave * 16 + srow) * K + schunk;
  const int lAoff = wave * 1024, lBoff = wave * 512;

  f32x4 aH[4][2] = {}, aG[4][2] = {};

  auto STAGE = [&](int buf, int t) {
    int k0 = t << 5;
    glds16(gA + k0, &As[buf][lAoff]);
    glds16(gA + 16 * K + k0, &As[buf][lAoff + 512]);
    glds16(gH + k0, &Hs[buf][lBoff]);
    glds16(gG + k0, &Gs[buf][lBoff]);
  };

  const int nt = K >> 5;
  STAGE(0, 0);
  STAGE(1, 1);

  int cur = 0;
  for (int t = 0; t < nt; ++t) {
    if (t + 2 < nt) {
      int sb = cur + 2; if (sb >= 3) sb -= 3;
      STAGE(sb, t + 2);
      asm volatile("s_waitcnt vmcnt(8)" ::: "memory");
    } else if (t + 2 == nt) {
      asm volatile("s_waitcnt vmcnt(4)" ::: "memory");
    } else {
      asm volatile("s_waitcnt vmcnt(0)" ::: "memory");
    }
    __builtin_amdgcn_s_barrier();
    __builtin_amdgcn_sched_barrier(0);

    bf16x8 af[4], hf[2], gf[2];
#pragma unroll
    for (int i = 0; i < 4; i++)
      af[i] = *(const bf16x8*)(&As[cur][(wm + i * 16 + l15) * 32 + 8 * lg]);
#pragma unroll
    for (int i = 0; i < 2; i++) {
      hf[i] = *(const bf16x8*)(&Hs[cur][(wn + i * 16 + l15) * 32 + 8 * lg]);
      gf[i] = *(const bf16x8*)(&Gs[cur][(wn + i * 16 + l15) * 32 + 8 * lg]);
    }
    __builtin_amdgcn_s_setprio(1);
#pragma unroll
    for (int mi = 0; mi < 4; mi++)
#pragma unroll
      for (int ni = 0; ni < 2; ni++) {
        aH[mi][ni] = __builtin_amdgcn_mfma_f32_16x16x32_bf16(af[mi], hf[ni],
                                                             aH[mi][ni], 0, 0, 0);
        aG[mi][ni] = __builtin_amdgcn_mfma_f32_16x16x32_bf16(af[mi], gf[ni],
                                                             aG[mi][ni], 0, 0, 0);
      }
    __builtin_amdgcn_s_setprio(0);
    asm volatile("s_waitcnt lgkmcnt(0)" ::: "memory");
    __builtin_amdgcn_sched_barrier(0);
    __builtin_amdgcn_s_barrier();
    cur = (cur == 2) ? 0 : cur + 1;
  }

  const int gr0 = bx * 128 + wm;
  const int gc0 = by * 64 + wn;
#pragma unroll
  for (int ni = 0; ni < 2; ni++) {
    int gc = gc0 + ni * 16 + l15;
    float bh = bH[gc], bg = bG[gc];
#pragma unroll
    for (int mi = 0; mi < 4; mi++) {
#pragma unroll
      for (int rr = 0; rr < 4; rr++) {
        int gr = gr0 + mi * 16 + 4 * lg + rr;
        float hv = aH[mi][ni][rr] + bh;
        float gv = aG[mi][ni][rr] + bg;
        float ge = 0.5f * gv * (1.f + erff(gv * 0.70710678118654752f));
        D[(long)gr * 2048 + gc] = (bf16)(hv * ge);
      }
    }
  }
}

// ---------------------------------------------------------------------------
// Flash attention v6: T15-style pipeline — QK(t+1) MFMAs issue before
// softmax(t) VALU so the chained MFMAs retire in softmax's shadow.
// 2 waves/block, 32 q-rows/wave, KV tiles of 64; K 2-buf + V 4-buf LDS;
// sA/sB register double-set via 2-unrolled phases (static indexing).
// ---------------------------------------------------------------------------
__global__ __launch_bounds__(128) void flash_attn(
    const bf16* __restrict__ Q, int ldq,
    const bf16* __restrict__ Kt, int ldk,
    const bf16* __restrict__ V,
    bf16* __restrict__ O,
    int Nq, int Nkv)
{
  int wid = xcd_swz_id(gridDim.x, gridDim.y);
  const int i0 = (wid % gridDim.x) * 64;
  const int bh = wid / gridDim.x;
  const int b = bh >> 3, h = bh & 7;
  const int lane = threadIdx.x & 63, wave = threadIdx.x >> 6;
  const int l31 = lane & 31, hi = lane >> 5;

  __shared__ bf16 Ks[2 * 64 * 64];   // 16 KB, K double-buffer
  __shared__ bf16 Vs[4 * 64 * 64];   // 32 KB, V quad-buffer (stage gap = 2 tiles)

  const bf16* Qb = Q + ((long)b * Nq + i0 + wave * 32) * ldq + h * 64;
  const bf16* Kb = Kt + (long)b * Nkv * ldk + h * 64;
  const bf16* Vb = V + ((long)b * 512 + h * 64) * Nkv;
  bf16* Ob = O + ((long)b * Nq + i0 + wave * 32) * 512 + h * 64;

  // Q B-fragments; scale*log2e folded -> softmax runs in exp2 domain
  const float QSC = 0.125f * 1.44269504f;
  bf16x8 qf[4];
#pragma unroll
  for (int ds = 0; ds < 4; ds++) {
    qf[ds] = *(const bf16x8*)(Qb + (long)l31 * ldq + ds * 16 + 8 * hi);
#pragma unroll
    for (int e = 0; e < 8; e++) qf[ds][e] = (bf16)((float)qf[ds][e] * QSC);
  }

  // staging: pre-swizzled global source, linear LDS dest; each wave stages
  // rows [wave*32, wave*32+32) of both K and V (8 loads per wave per tile)
  const int srow = lane >> 3;
  const int schk = (lane & 7) ^ srow;
  const long kOff = (long)srow * ldk + schk * 8;
  const long vOff = (long)srow * Nkv + schk * 8;

  const int nt = Nkv >> 6;

  auto STAGE_T = [&](int tile) {
    bf16* kd = Ks + (tile & 1) * 4096;
    bf16* vd = Vs + (tile & 3) * 4096;
    const long j = (long)tile * 64;
#pragma unroll
    for (int i = 0; i < 4; i++) {
      int r0 = wave * 32 + 8 * i;
      glds16(Kb + (j + r0) * ldk + kOff, kd + r0 * 64);
    }
#pragma unroll
    for (int i = 0; i < 4; i++) {
      int r0 = wave * 32 + 8 * i;
      glds16(Vb + (long)r0 * Nkv + j + vOff, vd + r0 * 64);
    }
  };

  f32x16 ot0 = {}, ot1 = {};
  float mrun = -1e30f, lrun = 0.f;

  auto QK = [&](f32x16& s0, f32x16& s1, int tile) {
    const bf16* kp = Ks + (tile & 1) * 4096;
    s0 = (f32x16){}; s1 = (f32x16){};
    __builtin_amdgcn_s_setprio(1);
#pragma unroll
    for (int ds = 0; ds < 4; ds++) {
      int ch = 2 * ds + hi;
      bf16x8 k0 = *(const bf16x8*)(kp + l31 * 64 + ((ch ^ (l31 & 7)) * 8));
      bf16x8 k1 = *(const bf16x8*)(kp + (32 + l31) * 64 + ((ch ^ (l31 & 7)) * 8));
      s0 = __builtin_amdgcn_mfma_f32_32x32x16_bf16(k0, qf[ds], s0, 0, 0, 0);
      s1 = __builtin_amdgcn_mfma_f32_32x32x16_bf16(k1, qf[ds], s1, 0, 0, 0);
    }
    __builtin_amdgcn_s_setprio(0);
  };

  auto SMPV = [&](f32x16& st0, f32x16& st1, int tile) {
    // row max: pairwise + tree
    float mx[8];
#pragma unroll
    for (int r = 0; r < 8; r++)
      mx[r] = fmaxf(fmaxf(st0[r], st0[r + 8]), fmaxf(st1[r], st1[r + 8]));
#pragma unroll
    for (int off = 4; off; off >>= 1)
#pragma unroll
      for (int r = 0; r < off; r++) mx[r] = fmaxf(mx[r], mx[r + off]);
    float rm = mx[0];
    { float2 pr = swap_halves(rm); rm = fmaxf(pr.x, pr.y); }

    bool pred = (rm <= mrun + 8.f);           // defer-max, log2 units
    if (!__all(pred)) {
      float mn = fmaxf(mrun, rm);
      float alpha = fexp2(mrun - mn);
      lrun *= alpha;
      mrun = mn;
#pragma unroll
      for (int r = 0; r < 16; r++) { ot0[r] *= alpha; ot1[r] *= alpha; }
    }
    float sm[8];
#pragma unroll
    for (int r = 0; r < 16; r++) {
      st0[r] = fexp2(st0[r] - mrun);
      st1[r] = fexp2(st1[r] - mrun);
    }
#pragma unroll
    for (int r = 0; r < 8; r++)
      sm[r] = (st0[r] + st0[r + 8]) + (st1[r] + st1[r + 8]);
#pragma unroll
    for (int off = 4; off; off >>= 1)
#pragma unroll
      for (int r = 0; r < off; r++) sm[r] += sm[r + off];
    { float2 pr = swap_halves(sm[0]); lrun += pr.x + pr.y; }

    // P -> bf16 B-fragments, O^T += V^T P^T
    const bf16* vp = Vs + (tile & 3) * 4096;
    __builtin_amdgcn_s_setprio(1);
#pragma unroll
    for (int c = 0; c < 4; c++) {
      const f32x16& sv = (c < 2) ? st0 : st1;
      const int base = (c & 1) * 8;
      unsigned a0 = pk_bf16(sv[base + 0], sv[base + 1]);
      unsigned b0 = pk_bf16(sv[base + 4], sv[base + 5]);
      unsigned a1 = pk_bf16(sv[base + 2], sv[base + 3]);
      unsigned b1 = pk_bf16(sv[base + 6], sv[base + 7]);
      plswap(a0, b0);
      plswap(a1, b1);
      uint4 wd = make_uint4(a0, a1, b0, b1);
      bf16x8 pB = *(bf16x8*)&wd;
      int ch = 2 * c + hi;
#pragma unroll
      for (int dt = 0; dt < 2; dt++) {
        int r = dt * 32 + l31;
        bf16x8 vf = *(const bf16x8*)(vp + r * 64 + ((ch ^ (l31 & 7)) * 8));
        if (dt == 0) ot0 = __builtin_amdgcn_mfma_f32_32x32x16_bf16(vf, pB, ot0, 0, 0, 0);
        else         ot1 = __builtin_amdgcn_mfma_f32_32x32x16_bf16(vf, pB, ot1, 0, 0, 0);
      }
    }
    __builtin_amdgcn_s_setprio(0);
  };

  // prologue: tiles 0,1 in flight; wait tile 0; QK(0)
  STAGE_T(0);
  STAGE_T(1);
  asm volatile("s_waitcnt vmcnt(8)");
  __builtin_amdgcn_s_barrier();
  __builtin_amdgcn_sched_barrier(0);
  f32x16 sA0, sA1, sB0, sB1;
  QK(sA0, sA1, 0);
  asm volatile("s_waitcnt lgkmcnt(0)");
  __builtin_amdgcn_s_barrier();       // QK(0) reads done before STAGE(2) writes Ks[0]

  for (int t = 0; t < nt; t += 2) {
    // ---- phase A: compute tile t (sA), prefetch QK(t+1) into sB ----
    if (t + 2 < nt) {
      STAGE_T(t + 2);
      asm volatile("s_waitcnt vmcnt(8)");     // tile t+1 resident
    } else if (t + 1 < nt) {
      asm volatile("s_waitcnt vmcnt(0)");
    }
    __builtin_amdgcn_s_barrier();
    __builtin_amdgcn_sched_barrier(0);
    if (t + 1 < nt) QK(sB0, sB1, t + 1);      // MFMA chain overlaps softmax(t)
    SMPV(sA0, sA1, t);
    asm volatile("s_waitcnt lgkmcnt(0)");
    __builtin_amdgcn_s_barrier();

    // ---- phase B: compute tile t+1 (sB), prefetch QK(t+2) into sA ----
    if (t + 1 < nt) {
      if (t + 3 < nt) {
        STAGE_T(t + 3);
        asm volatile("s_waitcnt vmcnt(8)");   // tile t+2 resident
      } else if (t + 2 < nt) {
        asm volatile("s_waitcnt vmcnt(0)");
      }
      __builtin_amdgcn_s_barrier();
      __builtin_amdgcn_sched_barrier(0);
      if (t + 2 < nt) QK(sA0, sA1, t + 2);
      SMPV(sB0, sB1, t + 1);
      asm volatile("s_waitcnt lgkmcnt(0)");
      __builtin_amdgcn_s_barrier();
    }
  }

  // O^T -> O via per-wave LDS transpose, coalesced store
  __syncthreads();
  bf16* Ow = Ks + wave * 2048;
  float inv = 1.0f / lrun;
#pragma unroll
  for (int dt = 0; dt < 2; dt++) {
#pragma unroll
    for (int r = 0; r < 16; r++) {
      int d = dt * 32 + (r & 3) + 8 * (r >> 2) + 4 * hi;
      float v = (dt == 0 ? ot0[r] : ot1[r]) * inv;
      Ow[l31 * 64 + (((d >> 3) ^ (l31 & 7)) * 8) + (d & 7)] = (bf16)v;
    }
  }
  __syncthreads();
#pragma unroll
  for (int i = 0; i < 4; i++) {
    int ch = hi * 4 + i;
    uint4 wd = *(const uint4*)(Ow + l31 * 64 + ((ch ^ (l31 & 7)) * 8));
    *(uint4*)(Ob + (long)l31 * 512 + ch * 8) = wd;
  }
}

// ---------------------------------------------------------------------------
// host
// ---------------------------------------------------------------------------
template <int BN>
static void launch_gemm(const bf16* A, long sAz, const bf16* B, long sBz,
                        int M, int N, int K, void* D, long sDz, int ldd, int Z,
                        const float* bias, const float* resid,
                        int mode, hipStream_t stream)
{
  gemm_nt<BN><<<dim3(M / 128, N / BN, Z), dim3(256), 0, stream>>>(
      A, sAz, B, sBz, M, N, K, D, sDz, ldd, bias, resid, mode);
}

extern "C" void kernel_launch(void* const* d_in, const int* in_sizes, int n_in,
                              void* d_out, int out_size, void* d_ws, size_t ws_size,
                              hipStream_t stream)
{
  (void)in_sizes; (void)n_in; (void)out_size; (void)ws_size;
  const float* x     = (const float*)d_in[0];
  const float* ctx   = (const float*)d_in[1];
  const float* g1    = (const float*)d_in[2];
  const float* Wq1f  = (const float*)d_in[3];
  const float* Wk1f  = (const float*)d_in[4];
  const float* Wv1f  = (const float*)d_in[5];
  const float* Wo1f  = (const float*)d_in[6];
  const float* bo1   = (const float*)d_in[7];
  const float* g2    = (const float*)d_in[8];
  const float* Wq2f  = (const float*)d_in[9];
  const float* Wk2f  = (const float*)d_in[10];
  const float* Wv2f  = (const float*)d_in[11];
  const float* Wo2f  = (const float*)d_in[12];
  const float* bo2   = (const float*)d_in[13];
  const float* g3    = (const float*)d_in[14];
  const float* Wff1f = (const float*)d_in[15];
  const float* bff1  = (const float*)d_in[16];
  const float* Wff2f = (const float*)d_in[17];
  const float* bff2  = (const float*)d_in[18];

  char* wsp = (char*)d_ws;
  size_t off = 0;
  auto alloc = [&](size_t bytes) -> void* {
    void* p = wsp + off;
    off += (bytes + 255) & ~(size_t)255;
    return p;
  };

  float* xt   = (float*)alloc((size_t)8192 * 512 * 4);
  float* x2   = (float*)alloc((size_t)8192 * 512 * 4);
  bf16* h     = (bf16*)alloc((size_t)8192 * 512 * 2);
  bf16* qkb   = (bf16*)alloc((size_t)8192 * 1024 * 2);
  bf16* qb    = (bf16*)alloc((size_t)8192 * 512 * 2);
  bf16* kb    = (bf16*)alloc((size_t)1024 * 512 * 2);
  bf16* vb    = (bf16*)alloc((size_t)8192 * 512 * 2);
  bf16* ao    = (bf16*)alloc((size_t)8192 * 512 * 2);
  bf16* ctxt  = (bf16*)alloc((size_t)1024 * 768 * 2);
  bf16* actb  = (bf16*)alloc((size_t)8192 * 2048 * 2);
  bf16* wqk1  = (bf16*)alloc((size_t)524288 * 2);
  bf16* wv1   = (bf16*)alloc((size_t)262144 * 2);
  bf16* wo1   = (bf16*)alloc((size_t)262144 * 2);
  bf16* wq2   = (bf16*)alloc((size_t)262144 * 2);
  bf16* wk2   = (bf16*)alloc((size_t)393216 * 2);
  bf16* wv2   = (bf16*)alloc((size_t)393216 * 2);
  bf16* wo2   = (bf16*)alloc((size_t)262144 * 2);
  bf16* wff1  = (bf16*)alloc((size_t)2097152 * 2);
  bf16* wff2  = (bf16*)alloc((size_t)1048576 * 2);

  {
    CvtPack p;
    const float* s[10] = {Wq1f, Wk1f, Wv1f, Wo1f, Wq2f, Wk2f, Wv2f, Wo2f, Wff1f, Wff2f};
    bf16* d[10] = {wqk1, wqk1 + 262144, wv1, wo1, wq2, wk2, wv2, wo2, wff1, wff2};
    int n[10] = {262144, 262144, 262144, 262144, 262144, 393216, 393216, 262144,
                 2097152, 1048576};
    int cum = 0;
    for (int i = 0; i < 10; i++) {
      p.src[i] = s[i]; p.dst[i] = d[i];
      cum += n[i] / 4; p.end4[i] = cum;
    }
    cvt_many<<<dim3((cum + 255) / 256), dim3(256), 0, stream>>>(p, cum);
  }

  transpose_k<float><<<dim3(64, 16, 4), dim3(256), 0, stream>>>(x, xt, 512, 2048);
  transpose_k<bf16><<<dim3(8, 24, 4), dim3(256), 0, stream>>>(ctx, ctxt, 768, 256);

  // ---- block 1: self attention ----
  ln_rows<<<dim3(2048), dim3(256), 0, stream>>>(xt, g1, h);
  launch_gemm<128>(h, 0, wqk1, 0, 8192, 1024, 512, qkb, 0, 1024, 1,
                   nullptr, nullptr, 0, stream);
  launch_gemm<64>(wv1, 0, h, (long)2048 * 512, 512, 2048, 512,
                  vb, (long)512 * 2048, 2048, 4, nullptr, nullptr, 0, stream);
  flash_attn<<<dim3(32, 32), dim3(128), 0, stream>>>(qkb, 1024, qkb + 512, 1024,
                                                     vb, ao, 2048, 2048);
  launch_gemm<64>(ao, 0, wo1, 0, 8192, 512, 512, x2, 0, 512, 1,
                  bo1, xt, 2, stream);

  // ---- block 2: cross attention ----
  ln_rows<<<dim3(2048), dim3(256), 0, stream>>>(x2, g2, h);
  launch_gemm<64>(h, 0, wq2, 0, 8192, 512, 512, qb, 0, 512, 1,
                  nullptr, nullptr, 0, stream);
  launch_gemm<64>(ctxt, 0, wk2, 0, 1024, 512, 768, kb, 0, 512, 1,
                  nullptr, nullptr, 0, stream);
  launch_gemm<64>(wv2, 0, ctxt, (long)256 * 768, 512, 256, 768,
                  vb, (long)512 * 256, 256, 4, nullptr, nullptr, 0, stream);
  flash_attn<<<dim3(32, 32), dim3(128), 0, stream>>>(qb, 512, kb, 512,
                                                     vb, ao, 2048, 256);
  launch_gemm<64>(ao, 0, wo2, 0, 8192, 512, 512, x2, 0, 512, 1,
                  bo2, x2, 2, stream);

  // ---- block 3: GEGLU FF (fused dual-GEMM) ----
  ln_rows<<<dim3(2048), dim3(256), 0, stream>>>(x2, g3, h);
  gemm_geglu<<<dim3(64, 32), dim3(256), 0, stream>>>(
      h, wff1, wff1 + (long)2048 * 512, bff1, bff1 + 2048, actb, 512);
  launch_gemm<64>(actb, 0, wff2, 0, 8192, 512, 2048, x2, 0, 512, 1,
                  bff2, x2, 2, stream);

  transpose_k<float><<<dim3(16, 64, 4), dim3(256), 0, stream>>>(x2, (float*)d_out,
                                                                2048, 512);
}

// Round 10
// 321.327 us; speedup vs baseline: 1.1143x; 1.1143x over previous
//
#include <hip/hip_runtime.h>
#include <hip/hip_bf16.h>

typedef __bf16 bf16;
typedef __attribute__((ext_vector_type(8))) __bf16 bf16x8;
typedef __attribute__((ext_vector_type(4))) __bf16 bf16x4;
typedef __attribute__((ext_vector_type(4))) float f32x4;
typedef __attribute__((ext_vector_type(16))) float f32x16;

// async global->LDS: stages 16B per lane; LDS dest = uniform base + lane*16
__device__ __forceinline__ void glds16(const bf16* g, bf16* l)
{
  __builtin_amdgcn_global_load_lds(
      (const __attribute__((address_space(1))) unsigned int*)g,
      (__attribute__((address_space(3))) unsigned int*)l, 16, 0, 0);
}

__device__ __forceinline__ unsigned pk_bf16(float lo, float hi)
{
  unsigned r;
  asm("v_cvt_pk_bf16_f32 %0, %1, %2" : "=v"(r) : "v"(lo), "v"(hi));
  return r;
}
__device__ __forceinline__ void plswap(unsigned& a, unsigned& b)
{
  asm volatile("v_permlane32_swap_b32 %0, %1" : "+v"(a), "+v"(b));
}
__device__ __forceinline__ float2 swap_halves(float x)
{
  unsigned a = __float_as_uint(x), b = a;
  plswap(a, b);
  return make_float2(__uint_as_float(a), __uint_as_float(b));
}
// raw v_exp_f32: 2^x, single instruction (exp2f() libcall was +15us, round 7)
__device__ __forceinline__ float fexp2(float x)
{
  float r;
  asm("v_exp_f32 %0, %1" : "=v"(r) : "v"(x));
  return r;
}

// bijective XCD-chunked remap of the flat workgroup id (m204 formula)
__device__ __forceinline__ int xcd_swz_id(int gx, int gy)
{
  int nwg = gx * gy;
  int bid = blockIdx.y * gx + blockIdx.x;
  int q = nwg >> 3, r = nwg & 7;
  int xcd = bid & 7, idx = bid >> 3;
  return (xcd < r) ? (xcd * (q + 1) + idx) : (r * (q + 1) + (xcd - r) * q + idx);
}

// ---------------------------------------------------------------------------
// merged weight convert f32 -> bf16 (10 segments, one launch)
// ---------------------------------------------------------------------------
struct CvtPack {
  const float* src[10];
  bf16* dst[10];
  int end4[10];
};

__global__ __launch_bounds__(256) void cvt_many(CvtPack p, int total4)
{
  int i = blockIdx.x * 256 + threadIdx.x;
  if (i >= total4) return;
  int s = 0;
#pragma unroll
  for (int k = 0; k < 9; k++) s += (i >= p.end4[k]) ? 1 : 0;
  int base = s ? p.end4[s - 1] : 0;
  long j = (long)(i - base) * 4;
  f32x4 v = *(const f32x4*)(p.src[s] + j);
  bf16x4 r;
  r.x = (bf16)v.x; r.y = (bf16)v.y; r.z = (bf16)v.z; r.w = (bf16)v.w;
  *(bf16x4*)(p.dst[s] + j) = r;
}

// ---------------------------------------------------------------------------
// transpose per z: in [R][C] f32 -> out [C][R] (f32 or bf16)
// ---------------------------------------------------------------------------
template <typename OutT>
__global__ __launch_bounds__(256) void transpose_k(const float* __restrict__ in,
                                                   OutT* __restrict__ out, int R, int C)
{
  __shared__ float tile[32][33];
  long zoff = (long)blockIdx.z * R * C;
  in += zoff; out += zoff;
  int c0 = blockIdx.x * 32, r0 = blockIdx.y * 32;
  int tx = threadIdx.x & 31, ty = threadIdx.x >> 5;
  for (int i = ty; i < 32; i += 8)
    tile[i][tx] = in[(long)(r0 + i) * C + c0 + tx];
  __syncthreads();
  for (int i = ty; i < 32; i += 8)
    out[(long)(c0 + i) * R + r0 + tx] = (OutT)tile[tx][i];
}

// ---------------------------------------------------------------------------
// LayerNorm rows of 512, fp32 in, bf16 out; one wave per row
// ---------------------------------------------------------------------------
__global__ __launch_bounds__(256) void ln_rows(const float* __restrict__ x,
                                               const float* __restrict__ g,
                                               bf16* __restrict__ out)
{
  int row = blockIdx.x * 4 + (threadIdx.x >> 6);
  int lane = threadIdx.x & 63;
  const float* xr = x + (long)row * 512;
  f32x4 a = *(const f32x4*)(xr + lane * 4);
  f32x4 b = *(const f32x4*)(xr + 256 + lane * 4);
  float s = a.x + a.y + a.z + a.w + b.x + b.y + b.z + b.w;
  float q = a.x*a.x + a.y*a.y + a.z*a.z + a.w*a.w
          + b.x*b.x + b.y*b.y + b.z*b.z + b.w*b.w;
#pragma unroll
  for (int off = 32; off; off >>= 1) {
    s += __shfl_xor(s, off);
    q += __shfl_xor(q, off);
  }
  float mean = s * (1.f / 512.f);
  float var  = q * (1.f / 512.f) - mean * mean;
  float rs = rsqrtf(var + 1e-5f);
  f32x4 ga = *(const f32x4*)(g + lane * 4);
  f32x4 gb = *(const f32x4*)(g + 256 + lane * 4);
  bf16* orow = out + (long)row * 512;
  bf16x4 r0, r1;
  r0.x = (bf16)((a.x - mean) * rs * ga.x);
  r0.y = (bf16)((a.y - mean) * rs * ga.y);
  r0.z = (bf16)((a.z - mean) * rs * ga.z);
  r0.w = (bf16)((a.w - mean) * rs * ga.w);
  r1.x = (bf16)((b.x - mean) * rs * gb.x);
  r1.y = (bf16)((b.y - mean) * rs * gb.y);
  r1.z = (bf16)((b.z - mean) * rs * gb.z);
  r1.w = (bf16)((b.w - mean) * rs * gb.w);
  *(bf16x4*)(orow + lane * 4) = r0;
  *(bf16x4*)(orow + 256 + lane * 4) = r1;
}

// ---------------------------------------------------------------------------
// NT GEMM: D[M][N] = A[M][K] * B[N][K]^T
// 3-buffer LDS, depth-2 counted vmcnt; XCD chunks span COL-tiles for a few
// ROW-stripes (bx = w/gy) so each XCD keeps its A-stripes L2-resident.
// ---------------------------------------------------------------------------
template <int BN>
__global__ __launch_bounds__(256) void gemm_nt(
    const bf16* __restrict__ A, long sAz,
    const bf16* __restrict__ B, long sBz,
    int M, int N, int K,
    void* __restrict__ Dp, long sDz, int ldd,
    const float* __restrict__ bias,
    const float* __restrict__ resid,
    int mode)
{
  constexpr int NI = BN / 32;
  __shared__ bf16 As[3][128 * 32];
  __shared__ bf16 Bs[3][BN * 32];
  const int tid = threadIdx.x;
  const int lane = tid & 63;
  const int wave = tid >> 6;
  const int l15 = lane & 15, lg = lane >> 4;
  const int wm = (wave & 1) << 6;
  const int wn = (BN == 128) ? ((wave >> 1) << 6) : ((wave >> 1) << 5);
  const long z = blockIdx.z;

  int bx, by;
  if (gridDim.z == 1) {
    int w = xcd_swz_id(gridDim.x, gridDim.y);
    bx = w / gridDim.y; by = w % gridDim.y;   // A-row-stripe stays on one XCD
  } else { bx = blockIdx.x; by = blockIdx.y; }

  const bf16* Ab = A + z * sAz + (long)(bx * 128) * K;
  const bf16* Bb = B + z * sBz + (long)(by * BN) * K;

  const int srow = lane >> 2;
  const int schunk = (lane & 3) * 8;
  const bf16* gA = Ab + (long)(wave * 32 + srow) * K + schunk;
  const int lAoff = wave * 1024;
  const bf16* gB;
  int lBoff;
  if (BN == 128) { gB = Bb + (long)(wave * 32 + srow) * K + schunk; lBoff = wave * 1024; }
  else           { gB = Bb + (long)(wave * 16 + srow) * K + schunk; lBoff = wave * 512; }

  f32x4 acc[4][NI] = {};

  auto STAGE = [&](int buf, int t) {
    int k0 = t << 5;
    glds16(gA + k0, &As[buf][lAoff]);
    glds16(gA + 16 * K + k0, &As[buf][lAoff + 512]);
    glds16(gB + k0, &Bs[buf][lBoff]);
    if (BN == 128) glds16(gB + 16 * K + k0, &Bs[buf][lBoff + 512]);
  };

  const int nt = K >> 5;
  STAGE(0, 0);
  STAGE(1, 1);

  int cur = 0;
  for (int t = 0; t < nt; ++t) {
    if (t + 2 < nt) {
      int sb = cur + 2; if (sb >= 3) sb -= 3;
      STAGE(sb, t + 2);
      if constexpr (BN == 128) asm volatile("s_waitcnt vmcnt(8)" ::: "memory");
      else                     asm volatile("s_waitcnt vmcnt(6)" ::: "memory");
    } else if (t + 2 == nt) {
      if constexpr (BN == 128) asm volatile("s_waitcnt vmcnt(4)" ::: "memory");
      else                     asm volatile("s_waitcnt vmcnt(3)" ::: "memory");
    } else {
      asm volatile("s_waitcnt vmcnt(0)" ::: "memory");
    }
    __builtin_amdgcn_s_barrier();
    __builtin_amdgcn_sched_barrier(0);

    bf16x8 af[4], bfr[NI];
#pragma unroll
    for (int i = 0; i < 4; i++)
      af[i] = *(const bf16x8*)(&As[cur][(wm + i * 16 + l15) * 32 + 8 * lg]);
#pragma unroll
    for (int i = 0; i < NI; i++)
      bfr[i] = *(const bf16x8*)(&Bs[cur][(wn + i * 16 + l15) * 32 + 8 * lg]);
    __builtin_amdgcn_s_setprio(1);
#pragma unroll
    for (int mi = 0; mi < 4; mi++)
#pragma unroll
      for (int ni = 0; ni < NI; ni++)
        acc[mi][ni] = __builtin_amdgcn_mfma_f32_16x16x32_bf16(af[mi], bfr[ni],
                                                              acc[mi][ni], 0, 0, 0);
    __builtin_amdgcn_s_setprio(0);
    asm volatile("s_waitcnt lgkmcnt(0)" ::: "memory");
    __builtin_amdgcn_sched_barrier(0);
    __builtin_amdgcn_s_barrier();
    cur = (cur == 2) ? 0 : cur + 1;
  }

  const int gr0 = bx * 128 + wm;
  const int gc0 = by * BN + wn;
#pragma unroll
  for (int ni = 0; ni < NI; ni++) {
    int gc = gc0 + ni * 16 + l15;
    float bv = bias ? bias[gc] : 0.f;
#pragma unroll
    for (int mi = 0; mi < 4; mi++) {
#pragma unroll
      for (int rr = 0; rr < 4; rr++) {
        int gr = gr0 + mi * 16 + 4 * lg + rr;
        long o = z * sDz + (long)gr * ldd + gc;
        float val = acc[mi][ni][rr] + bv;
        if (mode == 0) ((bf16*)Dp)[o] = (bf16)val;
        else           ((float*)Dp)[o] = val + resid[o];
      }
    }
  }
}

// ---------------------------------------------------------------------------
// Fused GEGLU dual-GEMM (chunk-orientation fix kept)
// ---------------------------------------------------------------------------
__global__ __launch_bounds__(256) void gemm_geglu(
    const bf16* __restrict__ A,
    const bf16* __restrict__ WH, const bf16* __restrict__ WG,
    const float* __restrict__ bH, const float* __restrict__ bG,
    bf16* __restrict__ D, int K)
{
  __shared__ bf16 As[3][128 * 32];
  __shared__ bf16 Hs[3][64 * 32];
  __shared__ bf16 Gs[3][64 * 32];
  const int tid = threadIdx.x;
  const int lane = tid & 63;
  const int wave = tid >> 6;
  const int l15 = lane & 15, lg = lane >> 4;
  const int wm = (wave & 1) << 6;
  const int wn = (wave >> 1) << 5;

  int w = xcd_swz_id(gridDim.x, gridDim.y);
  int bx = w / gridDim.y, by = w % gridDim.y;   // A-row-stripe per XCD

  const bf16* Ab = A + (long)(bx * 128) * K;
  const bf16* Hb = WH + (long)(by * 64) * K;
  const bf16* Gb = WG + (long)(by * 64) * K;

  const int srow = lane >> 2;
  const int schunk = (lane & 3) * 8;
  const bf16* gA = Ab + (long)(wave * 32 + srow) * K + schunk;
  const bf16* gH = Hb + (long)(wave * 16 + srow) * K + schunk;
  const bf16* gG = Gb + (long)(wave * 16 + srow) * K + schunk;
  const int lAoff = wave * 1024, lBoff = wave * 512;

  f32x4 aH[4][2] = {}, aG[4][2] = {};

  auto STAGE = [&](int buf, int t) {
    int k0 = t << 5;
    glds16(gA + k0, &As[buf][lAoff]);
    glds16(gA + 16 * K + k0, &As[buf][lAoff + 512]);
    glds16(gH + k0, &Hs[buf][lBoff]);
    glds16(gG + k0, &Gs[buf][lBoff]);
  };

  const int nt = K >> 5;
  STAGE(0, 0);
  STAGE(1, 1);

  int cur = 0;
  for (int t = 0; t < nt; ++t) {
    if (t + 2 < nt) {
      int sb = cur + 2; if (sb >= 3) sb -= 3;
      STAGE(sb, t + 2);
      asm volatile("s_waitcnt vmcnt(8)" ::: "memory");
    } else if (t + 2 == nt) {
      asm volatile("s_waitcnt vmcnt(4)" ::: "memory");
    } else {
      asm volatile("s_waitcnt vmcnt(0)" ::: "memory");
    }
    __builtin_amdgcn_s_barrier();
    __builtin_amdgcn_sched_barrier(0);

    bf16x8 af[4], hf[2], gf[2];
#pragma unroll
    for (int i = 0; i < 4; i++)
      af[i] = *(const bf16x8*)(&As[cur][(wm + i * 16 + l15) * 32 + 8 * lg]);
#pragma unroll
    for (int i = 0; i < 2; i++) {
      hf[i] = *(const bf16x8*)(&Hs[cur][(wn + i * 16 + l15) * 32 + 8 * lg]);
      gf[i] = *(const bf16x8*)(&Gs[cur][(wn + i * 16 + l15) * 32 + 8 * lg]);
    }
    __builtin_amdgcn_s_setprio(1);
#pragma unroll
    for (int mi = 0; mi < 4; mi++)
#pragma unroll
      for (int ni = 0; ni < 2; ni++) {
        aH[mi][ni] = __builtin_amdgcn_mfma_f32_16x16x32_bf16(af[mi], hf[ni],
                                                             aH[mi][ni], 0, 0, 0);
        aG[mi][ni] = __builtin_amdgcn_mfma_f32_16x16x32_bf16(af[mi], gf[ni],
                                                             aG[mi][ni], 0, 0, 0);
      }
    __builtin_amdgcn_s_setprio(0);
    asm volatile("s_waitcnt lgkmcnt(0)" ::: "memory");
    __builtin_amdgcn_sched_barrier(0);
    __builtin_amdgcn_s_barrier();
    cur = (cur == 2) ? 0 : cur + 1;
  }

  const int gr0 = bx * 128 + wm;
  const int gc0 = by * 64 + wn;
#pragma unroll
  for (int ni = 0; ni < 2; ni++) {
    int gc = gc0 + ni * 16 + l15;
    float bh = bH[gc], bg = bG[gc];
#pragma unroll
    for (int mi = 0; mi < 4; mi++) {
#pragma unroll
      for (int rr = 0; rr < 4; rr++) {
        int gr = gr0 + mi * 16 + 4 * lg + rr;
        float hv = aH[mi][ni][rr] + bh;
        float gv = aG[mi][ni][rr] + bg;
        float ge = 0.5f * gv * (1.f + erff(gv * 0.70710678118654752f));
        D[(long)gr * 2048 + gc] = (bf16)(hv * ge);
      }
    }
  }
}

// ---------------------------------------------------------------------------
// Flash attention (round-8 verbatim, measured 71.7us): 2-wave, 32 q-rows/wave,
// KV tiles of 64, per-wave full staging with vmcnt(8), exp2-domain softmax
// via raw v_exp_f32, tree reductions. T15 pipelining REVERTED (round 9:
// +56 VGPR, occ 19->11%, 72->101us — m253's negative transfer confirmed).
// ---------------------------------------------------------------------------
__global__ __launch_bounds__(128) void flash_attn(
    const bf16* __restrict__ Q, int ldq,
    const bf16* __restrict__ Kt, int ldk,
    const bf16* __restrict__ V,
    bf16* __restrict__ O,
    int Nq, int Nkv)
{
  int wid = xcd_swz_id(gridDim.x, gridDim.y);
  const int i0 = (wid % gridDim.x) * 64;
  const int bh = wid / gridDim.x;
  const int b = bh >> 3, h = bh & 7;
  const int lane = threadIdx.x & 63, wave = threadIdx.x >> 6;
  const int l31 = lane & 31, hi = lane >> 5;

  __shared__ bf16 Ks[2][64 * 64];
  __shared__ bf16 Vs[2][64 * 64];

  const bf16* Qb = Q + ((long)b * Nq + i0 + wave * 32) * ldq + h * 64;
  const bf16* Kb = Kt + (long)b * Nkv * ldk + h * 64;
  const bf16* Vb = V + ((long)b * 512 + h * 64) * Nkv;
  bf16* Ob = O + ((long)b * Nq + i0 + wave * 32) * 512 + h * 64;

  const float QSC = 0.125f * 1.44269504f;
  bf16x8 qf[4];
#pragma unroll
  for (int ds = 0; ds < 4; ds++) {
    qf[ds] = *(const bf16x8*)(Qb + (long)l31 * ldq + ds * 16 + 8 * hi);
#pragma unroll
    for (int e = 0; e < 8; e++) qf[ds][e] = (bf16)((float)qf[ds][e] * QSC);
  }

  const int srow = lane >> 3;
  const int schk = (lane & 7) ^ srow;
  const long kOff = (long)srow * ldk + schk * 8;
  const long vOff = (long)srow * Nkv + schk * 8;

  const int nt = Nkv >> 6;

#pragma unroll
  for (int i = 0; i < 4; i++) {
    int r0 = wave * 32 + 8 * i;
    glds16(Kb + (long)r0 * ldk + kOff, &Ks[0][r0 * 64]);
    glds16(Vb + (long)r0 * Nkv + vOff, &Vs[0][r0 * 64]);
  }

  f32x16 ot0 = {}, ot1 = {};
  float mrun = -1e30f, lrun = 0.f;

  for (int t = 0; t < nt; ++t) {
    const int cur = t & 1;
    if (t + 1 < nt) {
      const long j1 = (long)(t + 1) * 64;
#pragma unroll
      for (int i = 0; i < 4; i++) {
        int r0 = wave * 32 + 8 * i;
        glds16(Kb + (j1 + r0) * ldk + kOff, &Ks[cur ^ 1][r0 * 64]);
        glds16(Vb + (long)r0 * Nkv + j1 + vOff, &Vs[cur ^ 1][r0 * 64]);
      }
      asm volatile("s_waitcnt vmcnt(8)");      // current tile resident; next in flight
    } else {
      asm volatile("s_waitcnt vmcnt(0)");
    }
    __builtin_amdgcn_s_barrier();
    __builtin_amdgcn_sched_barrier(0);

    f32x16 st0 = {}, st1 = {};
    __builtin_amdgcn_s_setprio(1);
#pragma unroll
    for (int ds = 0; ds < 4; ds++) {
      int ch = 2 * ds + hi;
      bf16x8 k0 = *(const bf16x8*)(&Ks[cur][l31 * 64 + ((ch ^ (l31 & 7)) * 8)]);
      bf16x8 k1 = *(const bf16x8*)(&Ks[cur][(32 + l31) * 64 + ((ch ^ (l31 & 7)) * 8)]);
      st0 = __builtin_amdgcn_mfma_f32_32x32x16_bf16(k0, qf[ds], st0, 0, 0, 0);
      st1 = __builtin_amdgcn_mfma_f32_32x32x16_bf16(k1, qf[ds], st1, 0, 0, 0);
    }
    __builtin_amdgcn_s_setprio(0);

    float mx[8];
#pragma unroll
    for (int r = 0; r < 8; r++)
      mx[r] = fmaxf(fmaxf(st0[r], st0[r + 8]), fmaxf(st1[r], st1[r + 8]));
#pragma unroll
    for (int off = 4; off; off >>= 1)
#pragma unroll
      for (int r = 0; r < off; r++) mx[r] = fmaxf(mx[r], mx[r + off]);
    float rm = mx[0];
    { float2 pr = swap_halves(rm); rm = fmaxf(pr.x, pr.y); }

    bool pred = (rm <= mrun + 8.f);           // defer-max, log2 units
    if (!__all(pred)) {
      float mn = fmaxf(mrun, rm);
      float alpha = fexp2(mrun - mn);
      lrun *= alpha;
      mrun = mn;
#pragma unroll
      for (int r = 0; r < 16; r++) { ot0[r] *= alpha; ot1[r] *= alpha; }
    }
    float sm[8];
#pragma unroll
    for (int r = 0; r < 16; r++) {
      st0[r] = fexp2(st0[r] - mrun);
      st1[r] = fexp2(st1[r] - mrun);
    }
#pragma unroll
    for (int r = 0; r < 8; r++)
      sm[r] = (st0[r] + st0[r + 8]) + (st1[r] + st1[r + 8]);
#pragma unroll
    for (int off = 4; off; off >>= 1)
#pragma unroll
      for (int r = 0; r < off; r++) sm[r] += sm[r + off];
    { float2 pr = swap_halves(sm[0]); lrun += pr.x + pr.y; }

    __builtin_amdgcn_s_setprio(1);
#pragma unroll
    for (int c = 0; c < 4; c++) {
      const f32x16& sv = (c < 2) ? st0 : st1;
      const int base = (c & 1) * 8;
      unsigned a0 = pk_bf16(sv[base + 0], sv[base + 1]);
      unsigned b0 = pk_bf16(sv[base + 4], sv[base + 5]);
      unsigned a1 = pk_bf16(sv[base + 2], sv[base + 3]);
      unsigned b1 = pk_bf16(sv[base + 6], sv[base + 7]);
      plswap(a0, b0);
      plswap(a1, b1);
      uint4 wd = make_uint4(a0, a1, b0, b1);
      bf16x8 pB = *(bf16x8*)&wd;
      int ch = 2 * c + hi;
#pragma unroll
      for (int dt = 0; dt < 2; dt++) {
        int r = dt * 32 + l31;
        bf16x8 vf = *(const bf16x8*)(&Vs[cur][r * 64 + ((ch ^ (l31 & 7)) * 8)]);
        if (dt == 0) ot0 = __builtin_amdgcn_mfma_f32_32x32x16_bf16(vf, pB, ot0, 0, 0, 0);
        else         ot1 = __builtin_amdgcn_mfma_f32_32x32x16_bf16(vf, pB, ot1, 0, 0, 0);
      }
    }
    __builtin_amdgcn_s_setprio(0);
    asm volatile("s_waitcnt lgkmcnt(0)");
    __builtin_amdgcn_s_barrier();
  }

  __syncthreads();
  bf16* Ow = &Ks[0][wave * 2048];
  float inv = 1.0f / lrun;
#pragma unroll
  for (int dt = 0; dt < 2; dt++) {
#pragma unroll
    for (int r = 0; r < 16; r++) {
      int d = dt * 32 + (r & 3) + 8 * (r >> 2) + 4 * hi;
      float v = (dt == 0 ? ot0[r] : ot1[r]) * inv;
      Ow[l31 * 64 + (((d >> 3) ^ (l31 & 7)) * 8) + (d & 7)] = (bf16)v;
    }
  }
  __syncthreads();
#pragma unroll
  for (int i = 0; i < 4; i++) {
    int ch = hi * 4 + i;
    uint4 wd = *(const uint4*)(&Ow[l31 * 64 + ((ch ^ (l31 & 7)) * 8)]);
    *(uint4*)(Ob + (long)l31 * 512 + ch * 8) = wd;
  }
}

// ---------------------------------------------------------------------------
// host
// ---------------------------------------------------------------------------
template <int BN>
static void launch_gemm(const bf16* A, long sAz, const bf16* B, long sBz,
                        int M, int N, int K, void* D, long sDz, int ldd, int Z,
                        const float* bias, const float* resid,
                        int mode, hipStream_t stream)
{
  gemm_nt<BN><<<dim3(M / 128, N / BN, Z), dim3(256), 0, stream>>>(
      A, sAz, B, sBz, M, N, K, D, sDz, ldd, bias, resid, mode);
}

extern "C" void kernel_launch(void* const* d_in, const int* in_sizes, int n_in,
                              void* d_out, int out_size, void* d_ws, size_t ws_size,
                              hipStream_t stream)
{
  (void)in_sizes; (void)n_in; (void)out_size; (void)ws_size;
  const float* x     = (const float*)d_in[0];
  const float* ctx   = (const float*)d_in[1];
  const float* g1    = (const float*)d_in[2];
  const float* Wq1f  = (const float*)d_in[3];
  const float* Wk1f  = (const float*)d_in[4];
  const float* Wv1f  = (const float*)d_in[5];
  const float* Wo1f  = (const float*)d_in[6];
  const float* bo1   = (const float*)d_in[7];
  const float* g2    = (const float*)d_in[8];
  const float* Wq2f  = (const float*)d_in[9];
  const float* Wk2f  = (const float*)d_in[10];
  const float* Wv2f  = (const float*)d_in[11];
  const float* Wo2f  = (const float*)d_in[12];
  const float* bo2   = (const float*)d_in[13];
  const float* g3    = (const float*)d_in[14];
  const float* Wff1f = (const float*)d_in[15];
  const float* bff1  = (const float*)d_in[16];
  const float* Wff2f = (const float*)d_in[17];
  const float* bff2  = (const float*)d_in[18];

  char* wsp = (char*)d_ws;
  size_t off = 0;
  auto alloc = [&](size_t bytes) -> void* {
    void* p = wsp + off;
    off += (bytes + 255) & ~(size_t)255;
    return p;
  };

  float* xt   = (float*)alloc((size_t)8192 * 512 * 4);
  float* x2   = (float*)alloc((size_t)8192 * 512 * 4);
  bf16* h     = (bf16*)alloc((size_t)8192 * 512 * 2);
  bf16* qkb   = (bf16*)alloc((size_t)8192 * 1024 * 2);
  bf16* qb    = (bf16*)alloc((size_t)8192 * 512 * 2);
  bf16* kb    = (bf16*)alloc((size_t)1024 * 512 * 2);
  bf16* vb    = (bf16*)alloc((size_t)8192 * 512 * 2);
  bf16* ao    = (bf16*)alloc((size_t)8192 * 512 * 2);
  bf16* ctxt  = (bf16*)alloc((size_t)1024 * 768 * 2);
  bf16* actb  = (bf16*)alloc((size_t)8192 * 2048 * 2);
  bf16* wqk1  = (bf16*)alloc((size_t)524288 * 2);
  bf16* wv1   = (bf16*)alloc((size_t)262144 * 2);
  bf16* wo1   = (bf16*)alloc((size_t)262144 * 2);
  bf16* wq2   = (bf16*)alloc((size_t)262144 * 2);
  bf16* wk2   = (bf16*)alloc((size_t)393216 * 2);
  bf16* wv2   = (bf16*)alloc((size_t)393216 * 2);
  bf16* wo2   = (bf16*)alloc((size_t)262144 * 2);
  bf16* wff1  = (bf16*)alloc((size_t)2097152 * 2);
  bf16* wff2  = (bf16*)alloc((size_t)1048576 * 2);

  {
    CvtPack p;
    const float* s[10] = {Wq1f, Wk1f, Wv1f, Wo1f, Wq2f, Wk2f, Wv2f, Wo2f, Wff1f, Wff2f};
    bf16* d[10] = {wqk1, wqk1 + 262144, wv1, wo1, wq2, wk2, wv2, wo2, wff1, wff2};
    int n[10] = {262144, 262144, 262144, 262144, 262144, 393216, 393216, 262144,
                 2097152, 1048576};
    int cum = 0;
    for (int i = 0; i < 10; i++) {
      p.src[i] = s[i]; p.dst[i] = d[i];
      cum += n[i] / 4; p.end4[i] = cum;
    }
    cvt_many<<<dim3((cum + 255) / 256), dim3(256), 0, stream>>>(p, cum);
  }

  transpose_k<float><<<dim3(64, 16, 4), dim3(256), 0, stream>>>(x, xt, 512, 2048);
  transpose_k<bf16><<<dim3(8, 24, 4), dim3(256), 0, stream>>>(ctx, ctxt, 768, 256);

  // ---- block 1: self attention ----
  ln_rows<<<dim3(2048), dim3(256), 0, stream>>>(xt, g1, h);
  launch_gemm<128>(h, 0, wqk1, 0, 8192, 1024, 512, qkb, 0, 1024, 1,
                   nullptr, nullptr, 0, stream);
  launch_gemm<64>(wv1, 0, h, (long)2048 * 512, 512, 2048, 512,
                  vb, (long)512 * 2048, 2048, 4, nullptr, nullptr, 0, stream);
  flash_attn<<<dim3(32, 32), dim3(128), 0, stream>>>(qkb, 1024, qkb + 512, 1024,
                                                     vb, ao, 2048, 2048);
  launch_gemm<64>(ao, 0, wo1, 0, 8192, 512, 512, x2, 0, 512, 1,
                  bo1, xt, 2, stream);

  // ---- block 2: cross attention ----
  ln_rows<<<dim3(2048), dim3(256), 0, stream>>>(x2, g2, h);
  launch_gemm<64>(h, 0, wq2, 0, 8192, 512, 512, qb, 0, 512, 1,
                  nullptr, nullptr, 0, stream);
  launch_gemm<64>(ctxt, 0, wk2, 0, 1024, 512, 768, kb, 0, 512, 1,
                  nullptr, nullptr, 0, stream);
  launch_gemm<64>(wv2, 0, ctxt, (long)256 * 768, 512, 256, 768,
                  vb, (long)512 * 256, 256, 4, nullptr, nullptr, 0, stream);
  flash_attn<<<dim3(32, 32), dim3(128), 0, stream>>>(qb, 512, kb, 512,
                                                     vb, ao, 2048, 256);
  launch_gemm<64>(ao, 0, wo2, 0, 8192, 512, 512, x2, 0, 512, 1,
                  bo2, x2, 2, stream);

  // ---- block 3: GEGLU FF (fused dual-GEMM) ----
  ln_rows<<<dim3(2048), dim3(256), 0, stream>>>(x2, g3, h);
  gemm_geglu<<<dim3(64, 32), dim3(256), 0, stream>>>(
      h, wff1, wff1 + (long)2048 * 512, bff1, bff1 + 2048, actb, 512);
  launch_gemm<64>(actb, 0, wff2, 0, 8192, 512, 2048, x2, 0, 512, 1,
                  bff2, x2, 2, stream);

  transpose_k<float><<<dim3(16, 64, 4), dim3(256), 0, stream>>>(x2, (float*)d_out,
                                                                2048, 512);
}